// Round 1
// baseline (450.097 us; speedup 1.0000x reference)
//
#include <hip/hip_runtime.h>

// B=4096, P=10, LD=TD=512, DIN=2048, M1=B*P=40960, N1=512, K2=5120
typedef __attribute__((ext_vector_type(4))) float f32x4;
typedef __attribute__((ext_vector_type(8))) short short8;
typedef __attribute__((ext_vector_type(4))) short short4v;
typedef __attribute__((ext_vector_type(8))) unsigned short ushort8;

__device__ __forceinline__ unsigned short f2bf(float f) {
  unsigned u = __float_as_uint(f);
  u = (u + 0x7fffu + ((u >> 16) & 1u)) >> 16;  // RNE
  return (unsigned short)u;
}
__device__ __forceinline__ float bf2f(unsigned short h) {
  return __uint_as_float(((unsigned)h) << 16);
}

// W1 [2048][512] fp32 -> W1t2 bf16 tiled [kt=64][n=512][kk=32]
__global__ __launch_bounds__(256) void prep_w1_k(const float* __restrict__ W1,
                                                 unsigned short* __restrict__ W1t2) {
  int f = blockIdx.x * 256 + threadIdx.x;       // 1,048,576 threads exact
  int kt = f >> 14;
  int r = f & 16383;
  int n = r >> 5;
  int kk = r & 31;
  W1t2[f] = f2bf(W1[(kt * 32 + kk) * 512 + n]);
}

// W2 [5120][10] fp32 -> W2t bf16 [10][5120]
__global__ __launch_bounds__(256) void prep_w2_k(const float* __restrict__ W2,
                                                 unsigned short* __restrict__ W2t) {
  int f = blockIdx.x * 256 + threadIdx.x;       // 51,200 exact
  int j = f / 5120;
  int k = f - j * 5120;
  W2t[f] = f2bf(W2[k * 10 + j]);
}

// emb[m][n] = relu(ctx[m][:] @ W1[:][n] + b1[n]), ctx = concat(agent, lane, nghl, nghc)
// block: 512 thr (8 waves), BM=64, BN=512 (full), BK=32, 16x16x32 bf16 MFMA
__global__ __launch_bounds__(512) void gemm1_k(
    const float* __restrict__ agent, const float* __restrict__ lanec,
    const float* __restrict__ nghl, const float* __restrict__ nghc,
    const unsigned short* __restrict__ W1t2, const float* __restrict__ b1,
    unsigned short* __restrict__ emb)
{
  __shared__ __align__(16) short Alds[2][64][40];   // +8 pad: kills 8-way bank conflict
  const int tid = threadIdx.x;
  const int wid = tid >> 6;        // 0..7 -> n-slice of 64
  const int lane = tid & 63;
  const int m0 = blockIdx.x * 64;

  // staging: thread -> (row, 4 cols) of the 64x32 fp32 tile
  const int srow = tid >> 3;
  const int scol = (tid & 7) << 2;
  const int mrow = m0 + srow;
  const int rowoff = mrow * 512 + scol;
  const int rowoff_a = (mrow / 10) * 512 + scol;

  // MFMA fragment coords
  const int fr = lane & 15;
  const int fk = (lane >> 4) << 3;

  const unsigned short* Bbase = W1t2 + (wid * 64 + fr) * 32 + fk;

  auto loadA = [&](int kt) -> f32x4 {
    int k0 = kt << 5;
    const float* p;
    if (k0 < 512)       p = agent + rowoff_a + k0;
    else if (k0 < 1024) p = lanec + rowoff + (k0 - 512);
    else if (k0 < 1536) p = nghl  + rowoff + (k0 - 1024);
    else                p = nghc  + rowoff + (k0 - 1536);
    return *(const f32x4*)p;
  };

  f32x4 acc[4][4];
  #pragma unroll
  for (int i = 0; i < 4; ++i)
    #pragma unroll
    for (int j = 0; j < 4; ++j) acc[i][j] = (f32x4)0.f;

  // prologue: stage tile 0, prefetch A tiles 1,2 and B tile 0
  {
    f32x4 v = loadA(0);
    short4v w;
    #pragma unroll
    for (int i = 0; i < 4; ++i) w[i] = (short)f2bf(v[i]);
    *(short4v*)&Alds[0][srow][scol] = w;
  }
  f32x4 pf0 = loadA(1);
  f32x4 pf1 = loadA(2);
  short8 bpre[4];
  #pragma unroll
  for (int ni = 0; ni < 4; ++ni) bpre[ni] = *(const short8*)(Bbase + ni * 512);

  int cur = 0;
  for (int kt = 0; kt < 64; ++kt) {
    __syncthreads();
    short8 af[4];
    #pragma unroll
    for (int mi = 0; mi < 4; ++mi)
      af[mi] = *(const short8*)&Alds[cur][mi * 16 + fr][fk];
    short8 bc[4];
    #pragma unroll
    for (int ni = 0; ni < 4; ++ni) bc[ni] = bpre[ni];
    if (kt < 63) {
      const unsigned short* bp = Bbase + (kt + 1) * 16384;
      #pragma unroll
      for (int ni = 0; ni < 4; ++ni) bpre[ni] = *(const short8*)(bp + ni * 512);
    }
    f32x4 wv = pf0;
    pf0 = pf1;
    if (kt < 61) pf1 = loadA(kt + 3);
    #pragma unroll
    for (int mi = 0; mi < 4; ++mi)
      #pragma unroll
      for (int ni = 0; ni < 4; ++ni)
        acc[mi][ni] = __builtin_amdgcn_mfma_f32_16x16x32_bf16(af[mi], bc[ni], acc[mi][ni], 0, 0, 0);
    if (kt < 63) {
      short4v w;
      #pragma unroll
      for (int i = 0; i < 4; ++i) w[i] = (short)f2bf(wv[i]);
      *(short4v*)&Alds[cur ^ 1][srow][scol] = w;
    }
    cur ^= 1;
  }

  // epilogue: +b1, relu, bf16 store to ws
  float b1v[4];
  #pragma unroll
  for (int ni = 0; ni < 4; ++ni) b1v[ni] = b1[wid * 64 + ni * 16 + fr];
  const int r0 = (lane >> 4) << 2;
  #pragma unroll
  for (int mi = 0; mi < 4; ++mi) {
    #pragma unroll
    for (int r = 0; r < 4; ++r) {
      int m = m0 + mi * 16 + r0 + r;
      unsigned short* erow = emb + m * 512 + wid * 64 + fr;
      #pragma unroll
      for (int ni = 0; ni < 4; ++ni) {
        float v = acc[mi][ni][r] + b1v[ni];
        v = fmaxf(v, 0.f);
        erow[ni * 16] = f2bf(v);
      }
    }
  }
}

// logits[b][j] = emb_flat[b][:] . W2t[j][:] + b2[j]; one wave per b
__global__ __launch_bounds__(256) void logits_k(
    const unsigned short* __restrict__ emb, const unsigned short* __restrict__ W2t,
    const float* __restrict__ b2, float* __restrict__ out)
{
  int b = (blockIdx.x * 256 + threadIdx.x) >> 6;
  int lane = threadIdx.x & 63;
  float acc[10];
  #pragma unroll
  for (int j = 0; j < 10; ++j) acc[j] = 0.f;
  const unsigned short* erow = emb + b * 5120 + lane * 8;
  const unsigned short* wbase = W2t + lane * 8;
  #pragma unroll
  for (int i = 0; i < 10; ++i) {
    ushort8 ev = *(const ushort8*)(erow + i * 512);
    float ef[8];
    #pragma unroll
    for (int t = 0; t < 8; ++t) ef[t] = bf2f(ev[t]);
    #pragma unroll
    for (int j = 0; j < 10; ++j) {
      ushort8 wv = *(const ushort8*)(wbase + j * 5120 + i * 512);
      #pragma unroll
      for (int t = 0; t < 8; ++t) acc[j] = fmaf(ef[t], bf2f(wv[t]), acc[j]);
    }
  }
  #pragma unroll
  for (int j = 0; j < 10; ++j)
    #pragma unroll
    for (int m = 1; m < 64; m <<= 1) acc[j] += __shfl_xor(acc[j], m, 64);
  if (lane == 0) {
    #pragma unroll
    for (int j = 0; j < 10; ++j) out[b * 10 + j] = acc[j] + b2[j];
  }
}

// gather best-lane rows (exact fp32 copies). out layout: [logits 40960][bl][bnl][bnc]
__global__ __launch_bounds__(384) void gather_k(
    const float* __restrict__ lanec, const float* __restrict__ nghl,
    const float* __restrict__ nghc, const int* __restrict__ label,
    float* __restrict__ out)
{
  int b = blockIdx.x;
  const int* lb = label + b * 10;
  int idx = 0;
  #pragma unroll
  for (int j = 9; j >= 0; --j) if (lb[j] == 1) idx = j;  // first 1 (one-hot)
  int g = threadIdx.x >> 7;            // 0..2 selects tensor
  int i = (threadIdx.x & 127) << 2;    // 128 float4 per 512-row
  const float* src = (g == 0 ? lanec : (g == 1 ? nghl : nghc)) + (b * 10 + idx) * 512 + i;
  float* dst = out + (g == 0 ? 40960 : (g == 1 ? 2138112 : 4235264)) + b * 512 + i;
  *(f32x4*)dst = *(const f32x4*)src;
}

extern "C" void kernel_launch(void* const* d_in, const int* in_sizes, int n_in,
                              void* d_out, int out_size, void* d_ws, size_t ws_size,
                              hipStream_t stream) {
  const float* agent = (const float*)d_in[0];
  const float* lanec = (const float*)d_in[1];
  const float* nghl  = (const float*)d_in[2];
  const float* nghc  = (const float*)d_in[3];
  const int*   label = (const int*)d_in[4];
  const float* W1    = (const float*)d_in[5];
  const float* b1    = (const float*)d_in[6];
  const float* W2    = (const float*)d_in[7];
  const float* b2    = (const float*)d_in[8];
  float* out = (float*)d_out;

  // ws carve: emb bf16 [40960][512] = 41,943,040 B; W1t2 = 2,097,152 B; W2t = 102,400 B
  unsigned short* emb  = (unsigned short*)d_ws;
  unsigned short* W1t2 = (unsigned short*)((char*)d_ws + 41943040);
  unsigned short* W2t  = (unsigned short*)((char*)d_ws + 41943040 + 2097152);

  prep_w1_k<<<4096, 256, 0, stream>>>(W1, W1t2);
  prep_w2_k<<<200, 256, 0, stream>>>(W2, W2t);
  gemm1_k<<<640, 512, 0, stream>>>(agent, lanec, nghl, nghc, W1t2, b1, emb);
  logits_k<<<1024, 256, 0, stream>>>(emb, W2t, b2, out);
  gather_k<<<4096, 384, 0, stream>>>(lanec, nghl, nghc, label, out);
}